// Round 7
// baseline (629.659 us; speedup 1.0000x reference)
//
#include <hip/hip_runtime.h>

typedef unsigned short u16;
typedef unsigned int u32;
typedef __attribute__((ext_vector_type(8))) short bf16x8;
typedef __attribute__((ext_vector_type(4))) float f32x4;
typedef __attribute__((ext_vector_type(8))) u16 u16x8;
typedef __attribute__((ext_vector_type(4))) u16 u16x4;

#define DEV __device__ __forceinline__

DEV u16 f2bf(float f) {
  u32 x = __float_as_uint(f);
  return (u16)((x + 0x7fffu + ((x >> 16) & 1u)) >> 16);  // RNE
}

// B=8 S=512 H=768 E=8 F=3072 K=2. fp32 I/O; bf16 MFMA internals.
// r12: single variable vs r11 — drop LDS double-buffer (64->32 KB/block)
// to get 4 blocks/CU (m97 structure: cross-block wave overlap IS the
// pipeline; m99/m100 showed explicit dbuf adds nothing). Keep r11's bf16
// native weights, in-register B repack, counted vmcnt (B(t+1) loads in
// flight across barriers), XCD mapping. gemm1 LDS-bounce epilogue split
// into two column-halves to fit 32 KB.

// ---------- prep: [0,1152) W1 conv; [1152,2304) W2 conv; rest hidden+pool ----
__global__ void prep_kernel(const float* __restrict__ W1, u16* __restrict__ w1b,
                            const float* __restrict__ W2, u16* __restrict__ w2b,
                            const float* __restrict__ hidden, u16* __restrict__ hbf,
                            float* __restrict__ pooled) {
  const int bid = blockIdx.x, t = threadIdx.x;
  if (bid < 2304) {  // 8*768*3072 floats each = 1152 blocks * 16384
    const float* src = (bid < 1152) ? W1 : W2;
    u16* dst = (bid < 1152) ? w1b : w2b;
    const size_t base = (size_t)(bid < 1152 ? bid : bid - 1152) * 16384 + t * 4;
#pragma unroll
    for (int i = 0; i < 16; ++i) {
      const float4 v = *(const float4*)(src + base + (size_t)i * 1024);
      u16x4 o; o[0] = f2bf(v.x); o[1] = f2bf(v.y); o[2] = f2bf(v.z); o[3] = f2bf(v.w);
      *(u16x4*)(dst + base + (size_t)i * 1024) = o;
    }
    return;
  }
  if (t >= 192) return;  // convert role uses 192 lanes
  const int u = bid - 2304;                 // 512 units: 8 rows each
  const int b = u >> 6, chunk = u & 63;
  const size_t base = (size_t)b * 512 * 768 + (size_t)chunk * 8 * 768 + t * 4;
  float ax = 0.f, ay = 0.f, az = 0.f, aw = 0.f;
#pragma unroll
  for (int r = 0; r < 8; ++r) {
    const float4 v = *(const float4*)(hidden + base + r * 768);
    ax += v.x; ay += v.y; az += v.z; aw += v.w;
    u16x4 o; o[0] = f2bf(v.x); o[1] = f2bf(v.y); o[2] = f2bf(v.z); o[3] = f2bf(v.w);
    *(u16x4*)(hbf + base + r * 768) = o;
  }
  float* p = pooled + b * 768 + t * 4;
  atomicAdd(p + 0, ax); atomicAdd(p + 1, ay);
  atomicAdd(p + 2, az); atomicAdd(p + 3, aw);
}

// ---------- router finalize ----------
__global__ void router_final_kernel(const float* __restrict__ pooled, const float* __restrict__ Wg,
                                    float* __restrict__ logits_out, int* __restrict__ sel,
                                    float* __restrict__ wsel) {
  __shared__ float l8[64];
  const int tid = threadIdx.x;
  const int b = tid >> 5, r = tid & 31, e = r >> 2, q = r & 3;
  float p = 0.f;
  for (int h = q * 192; h < q * 192 + 192; ++h) p += pooled[b * 768 + h] * Wg[h * 8 + e];
  p += __shfl_xor(p, 1);
  p += __shfl_xor(p, 2);
  if (q == 0) {
    const float lg = p * (1.f / 512.f);
    l8[b * 8 + e] = lg;
    logits_out[b * 8 + e] = lg;
  }
  __syncthreads();
  if (tid < 8) {
    const int bb = tid;
    float mx = -1e30f;
    for (int i = 0; i < 8; ++i) mx = fmaxf(mx, l8[bb * 8 + i]);
    float w[8], ssum = 0.f;
    for (int i = 0; i < 8; ++i) { w[i] = __expf(l8[bb * 8 + i] - mx); ssum += w[i]; }
    for (int i = 0; i < 8; ++i) w[i] /= ssum;
    int i0 = 0;
    for (int i = 1; i < 8; ++i) if (w[i] > w[i0]) i0 = i;   // first-occurrence ties
    int i1 = (i0 == 0) ? 1 : 0;
    for (int i = 0; i < 8; ++i) if (i != i0 && w[i] > w[i1]) i1 = i;
    sel[bb * 2 + 0] = i0; sel[bb * 2 + 1] = i1;
    wsel[bb * 2 + 0] = w[i0]; wsel[bb * 2 + 1] = w[i1];
  }
}

// ---------- GEMM building blocks (128x128 tile, BK=64, 256 thr) ----------
// LDS: A single 8192 u16 + B single 8192 u16 = 32 KB -> 4 blocks/CU.
// Slot swizzle phys = logical ^ (row&7) on 16B slots (r0-proven reader).

// A: bf16 source, global_load_lds (4 dma instrs), source pre-swizzled.
DEV void stage_A(const u16* __restrict__ g, int ld, int row0, int k0,
                 u16* l, int tid) {
  const int crow = tid >> 3;                       // 0..31
  const int swz = ((tid & 7) ^ (crow & 7)) * 8;
  const int wbase = tid & ~63;
  const u16* gb = g + (size_t)(row0 + crow) * ld + k0 + swz;
#pragma unroll
  for (int i = 0; i < 4; ++i) {
    __builtin_amdgcn_global_load_lds(
        (const __attribute__((address_space(1))) void*)(gb + (size_t)i * 32 * ld),
        (__attribute__((address_space(3))) void*)(l + (i * 256 + wbase) * 8), 16, 0, 0);
  }
}

// B: native bf16 [k][n]. issue: 16 dword loads (2 cols x 8 k-rows x 2 groups),
// 128 B contiguous per 32-lane row segment.
DEV void bT_issue(const u16* __restrict__ src, int ld, int c0, int k0, int tid,
                  u32 (&v)[16]) {
  const int c = c0 + (tid & 31) * 2;
  const int r0 = k0 + (tid >> 5) * 8;
#pragma unroll
  for (int fh = 0; fh < 2; ++fh)
#pragma unroll
    for (int r = 0; r < 8; ++r)
      v[fh * 8 + r] = *(const u32*)(src + (size_t)(r0 + r) * ld + c + fh * 64);
}

// commit: pure bf16 bit-repack (no rounding) -> 4x ds_write_b128 swizzled.
// Write conflicts: 8 consecutive lanes -> 4 distinct slots = 2-way (free).
DEV void bT_commit(int tid, const u32 (&v)[16], u16* Bs) {
  const int s = tid >> 5;  // k-oct 0..7
#pragma unroll
  for (int fh = 0; fh < 2; ++fh) {
    const int fA = (tid & 31) * 2 + fh * 64;
    u32 lo[4], hi[4];
#pragma unroll
    for (int q = 0; q < 4; ++q) {
      const u32 a = v[fh * 8 + 2 * q], b = v[fh * 8 + 2 * q + 1];
      lo[q] = (a & 0xffffu) | (b << 16);
      hi[q] = (a >> 16) | (b & 0xffff0000u);
    }
    uint4 ox = {lo[0], lo[1], lo[2], lo[3]};
    uint4 oy = {hi[0], hi[1], hi[2], hi[3]};
    *(uint4*)(Bs + fA * 64 + ((s ^ (fA & 7)) * 8)) = ox;
    *(uint4*)(Bs + (fA + 1) * 64 + ((s ^ ((fA + 1) & 7)) * 8)) = oy;
  }
}

// One K-tile: 32 MFMA, setprio-wrapped. Reader identical to r0.
DEV void tile_compute(const u16* As, const u16* Bs, int wm, int wn, int mi, int kq,
                      f32x4 (&acc)[4][4]) {
  bf16x8 af[4][2], bfr[4][2];
#pragma unroll
  for (int mt = 0; mt < 4; ++mt) {
    const int row = wm + mt * 16 + mi;
#pragma unroll
    for (int ks = 0; ks < 2; ++ks) {
      const int slot = (ks * 4 + kq) ^ (row & 7);
      af[mt][ks] = *(const bf16x8*)(As + row * 64 + slot * 8);
    }
  }
#pragma unroll
  for (int nt = 0; nt < 4; ++nt) {
    const int row = wn + nt * 16 + mi;
#pragma unroll
    for (int ks = 0; ks < 2; ++ks) {
      const int slot = (ks * 4 + kq) ^ (row & 7);
      bfr[nt][ks] = *(const bf16x8*)(Bs + row * 64 + slot * 8);
    }
  }
  __builtin_amdgcn_s_setprio(1);
#pragma unroll
  for (int ks = 0; ks < 2; ++ks)
#pragma unroll
    for (int mt = 0; mt < 4; ++mt)
#pragma unroll
      for (int nt = 0; nt < 4; ++nt)
        acc[mt][nt] = __builtin_amdgcn_mfma_f32_16x16x32_bf16(af[mt][ks], bfr[nt][ks], acc[mt][nt], 0, 0, 0);
  __builtin_amdgcn_s_setprio(0);
}

// m97-style single-buffer loop. Per tile: barrier (all waves done reading
// smem) -> stage A(t) dma -> commit B(t) (its 16 loads have been in flight
// one full iteration) -> issue B(t+1) -> vmcnt(16) retires A-dma, keeps the
// 16 B-loads in flight -> barrier -> 32 MFMA. Cross-block overlap (4/CU)
// hides the stage latency (m114).
#define GEMM_LOOP(NT, Aptr, Ald, Am0, Bptr, Bld, Bn0, KB)                         \
  bT_issue(Bptr, Bld, Bn0, (KB), tid, v);                                         \
  for (int t = 0; t < (NT); ++t) {                                                \
    __builtin_amdgcn_sched_barrier(0);                                            \
    __builtin_amdgcn_s_barrier();                                                 \
    __builtin_amdgcn_sched_barrier(0);                                            \
    stage_A(Aptr, Ald, Am0, (KB) + t * 64, As, tid);                              \
    bT_commit(tid, v, Bs);                                                        \
    if (t + 1 < (NT)) {                                                           \
      bT_issue(Bptr, Bld, Bn0, (KB) + (t + 1) * 64, tid, v);                      \
      asm volatile("s_waitcnt vmcnt(16) lgkmcnt(0)" ::: "memory");                \
    } else {                                                                      \
      asm volatile("s_waitcnt vmcnt(0) lgkmcnt(0)" ::: "memory");                 \
    }                                                                             \
    __builtin_amdgcn_sched_barrier(0);                                            \
    __builtin_amdgcn_s_barrier();                                                 \
    __builtin_amdgcn_sched_barrier(0);                                            \
    tile_compute(As, Bs, wm, wn, mi, kq, acc);                                    \
  }

// ---------- GEMM1: 1536 blocks, XCD x owns batch x's 2 pairs ----------
// xcd=bid&7, slot=bid>>3 (0..191), p=xcd*2+slot/96, tt=slot%96,
// m0=(tt/24)*128, n0=(tt%24)*128. B = w1b[e] native [768][3072] bf16.
__global__ __launch_bounds__(256, 4) void gemm1_kernel(
    const u16* __restrict__ hbf, const u16* __restrict__ w1b,
    const float* __restrict__ b1, u16* __restrict__ hbuf,
    const int* __restrict__ sel, const float* __restrict__ wsel) {
  __shared__ __align__(16) u16 smem[16384];  // 32 KB
  u16* As = smem;            // 8192 u16
  u16* Bs = smem + 8192;     // 8192 u16
  const int tid = threadIdx.x, bid = blockIdx.x;
  const int xcd = bid & 7, slot = bid >> 3;
  const int p = xcd * 2 + slot / 96;
  const int tt = slot % 96;
  const int m0 = (tt / 24) * 128, n0 = (tt % 24) * 128;
  const int b = p >> 1;
  const int e = sel[p];
  const float wgt = wsel[p];
  const u16* A = hbf + (size_t)b * 512 * 768;
  const u16* Bn = w1b + (size_t)e * 768 * 3072;   // native [h=768][f=3072]
  const int lane = tid & 63, wv = tid >> 6;
  const int wm = (wv >> 1) * 64, wn = (wv & 1) * 64;
  const int mi = lane & 15, kq = lane >> 4;

  f32x4 acc[4][4] = {};
  u32 v[16];
  GEMM_LOOP(12, A, 768, m0, Bn, 3072, n0, 0)

  // epilogue: C -> LDS (stride 68, two column-halves) -> coalesced u16x8 stores
  const float* b1e = b1 + e * 3072;
  u16* C = hbuf + (size_t)p * 512 * 3072;
  u16* cs = smem;  // 128*68 u16 = 17408 <= 16384? no: 17408 > 16384 -> use full smem (16384*2B=32KB; 17408*2=34816B) NOT OK
  // stride 64 with col-swizzle instead: cs[row*64 + (colL ^ ((row&3)*16... keep simple:
  // use stride 66: 128*66 = 8448 u16 per half? half covers 64 cols: [128][66] = 8448 <= 16384 OK
#pragma unroll
  for (int half = 0; half < 2; ++half) {
    __syncthreads();
    if ((wn >> 6) == half) {
#pragma unroll
      for (int nt = 0; nt < 4; ++nt) {
        const int colL = nt * 16 + mi;                 // 0..63 within half
        const float bias = b1e[n0 + half * 64 + colL];
#pragma unroll
        for (int mt = 0; mt < 4; ++mt) {
#pragma unroll
          for (int r = 0; r < 4; ++r) {
            const int row = wm + mt * 16 + kq * 4 + r; // C/D: col=lane&15, row=quad*4+reg
            const float x = acc[mt][nt][r] + bias;
            const float g = 0.5f * x * (1.f + erff(x * 0.70710678118654752f));  // exact GELU
            cs[row * 66 + colL] = f2bf(wgt * g);
          }
        }
      }
    }
    __syncthreads();
#pragma unroll
    for (int i = 0; i < 4; ++i) {
      const int idx = i * 256 + tid;
      const int row = idx >> 3, c8 = (idx & 7) * 8;
      *(u16x8*)(C + (size_t)(m0 + row) * 3072 + n0 + half * 64 + c8) =
          *(const u16x8*)(cs + row * 66 + c8);
    }
  }
}

// ---------- GEMM2: split-K x4, 768 blocks, fp32 atomics ----------
// xcd=bid&7 (= batch), slot=bid>>3 (0..95), ks=slot/24, tt=slot%24,
// m0=(tt/6)*128, n0=(tt%6)*128. kslot=ks>>1 expert, kbase=(ks&1)*1536.
// B = w2b[e] native [3072][768] bf16. ks==0 adds weighted bias.
__global__ __launch_bounds__(256, 4) void gemm2_kernel(
    const u16* __restrict__ hbuf, const u16* __restrict__ w2b,
    const float* __restrict__ b2, float* __restrict__ out,
    const int* __restrict__ sel, const float* __restrict__ wsel) {
  __shared__ __align__(16) u16 smem[16384];  // 32 KB
  u16* As = smem;
  u16* Bs = smem + 8192;
  const int tid = threadIdx.x, bid = blockIdx.x;
  const int b = bid & 7, slot = bid >> 3;
  const int ks = slot / 24, tt = slot % 24;
  const int m0 = (tt / 6) * 128, n0 = (tt % 6) * 128;
  const int kslot = ks >> 1;
  const int e = sel[b * 2 + kslot];
  const u16* A = hbuf + (size_t)(b * 2 + kslot) * 512 * 3072;
  const u16* Bn = w2b + (size_t)e * 3072 * 768;   // native [f=3072][h=768]
  const int kbase = (ks & 1) * 1536;
  const int lane = tid & 63, wv = tid >> 6;
  const int wm = (wv >> 1) * 64, wn = (wv & 1) * 64;
  const int mi = lane & 15, kq = lane >> 4;

  f32x4 acc[4][4] = {};
  u32 v[16];
  GEMM_LOOP(24, A, 3072, m0, Bn, 768, n0, kbase)

  float* C = out + (size_t)b * 512 * 768;
  const float w0 = wsel[b * 2 + 0], w1 = wsel[b * 2 + 1];
  const float* b2e0 = b2 + sel[b * 2 + 0] * 768;
  const float* b2e1 = b2 + sel[b * 2 + 1] * 768;
#pragma unroll
  for (int nt = 0; nt < 4; ++nt) {
    const int col = n0 + wn + nt * 16 + mi;
    const float bias = (ks == 0) ? (w0 * b2e0[col] + w1 * b2e1[col]) : 0.f;
#pragma unroll
    for (int mt = 0; mt < 4; ++mt) {
#pragma unroll
      for (int r = 0; r < 4; ++r) {
        const int row = m0 + wm + mt * 16 + kq * 4 + r;
        atomicAdd(&C[(size_t)row * 768 + col], acc[mt][nt][r] + bias);
      }
    }
  }
}

extern "C" void kernel_launch(void* const* d_in, const int* in_sizes, int n_in,
                              void* d_out, int out_size, void* d_ws, size_t ws_size,
                              hipStream_t stream) {
  const float* hidden = (const float*)d_in[0];  // [8,512,768] fp32
  const float* Wg     = (const float*)d_in[1];  // [768,8]
  const float* W1     = (const float*)d_in[2];  // [8,768,3072]
  const float* b1     = (const float*)d_in[3];  // [8,3072]
  const float* W2     = (const float*)d_in[4];  // [8,3072,768]
  const float* b2     = (const float*)d_in[5];  // [8,768]
  float* out = (float*)d_out;                   // [8,512,768] ++ logits [8,8]

  char* ws = (char*)d_ws;
  int*   sel    = (int*)ws;
  float* wsel   = (float*)(ws + 64);
  float* pooled = (float*)(ws + 128);
  u16* hbf  = (u16*)(ws + 32768);               // 6.29 MB bf16 hidden
  u16* w1b  = hbf + (size_t)8 * 512 * 768;      // 37.75 MB bf16 W1 (native)
  u16* w2b  = w1b + (size_t)8 * 768 * 3072;     // 37.75 MB bf16 W2 (native)
  u16* hbuf = w2b + (size_t)8 * 768 * 3072;     // 50.33 MB bf16 activations

  float* logits_out = out + (size_t)8 * 512 * 768;

  hipMemsetAsync(ws, 0, 32768, stream);                  // sel/wsel/pooled
  hipMemsetAsync(out, 0, (size_t)out_size * 4, stream);  // atomic accum base
  prep_kernel<<<2816, 256, 0, stream>>>(W1, w1b, W2, w2b, hidden, hbf, pooled);
  router_final_kernel<<<1, 256, 0, stream>>>(pooled, Wg, logits_out, sel, wsel);
  gemm1_kernel<<<1536, 256, 0, stream>>>(hbf, w1b, b1, hbuf, sel, wsel);
  gemm2_kernel<<<768, 256, 0, stream>>>(hbuf, w2b, b2, out, sel, wsel);
}

// Round 9
// 363.590 us; speedup vs baseline: 1.7318x; 1.7318x over previous
//
#include <hip/hip_runtime.h>

typedef unsigned short u16;
typedef unsigned int u32;
typedef __attribute__((ext_vector_type(8))) short bf16x8;
typedef __attribute__((ext_vector_type(4))) float f32x4;
typedef __attribute__((ext_vector_type(8))) u16 u16x8;
typedef __attribute__((ext_vector_type(4))) u16 u16x4;

#define DEV __device__ __forceinline__

DEV u16 f2bf(float f) {
  u32 x = __float_as_uint(f);
  return (u16)((x + 0x7fffu + ((x >> 16) & 1u)) >> 16);  // RNE
}

// B=8 S=512 H=768 E=8 F=3072 K=2. fp32 I/O; bf16 MFMA internals.
// r13 (resubmit after broker timeout): r12 with the spill fixed —
// __launch_bounds__(256,2) (r12's (256,4) capped VGPR at 64 -> acc spilled
// to scratch: WRITE 437MB, MfmaUtil 5.6%). Keeps: 32KB single-buffer LDS
// (5 blocks/CU), bf16 native weights from prep, in-register B repack,
// counted vmcnt (B(t+1) loads in flight across barriers), XCD mapping,
// LDS-bounced coalesced gemm1 stores.

// ---------- prep: [0,1152) W1 conv; [1152,2304) W2 conv; rest hidden+pool ----
__global__ void prep_kernel(const float* __restrict__ W1, u16* __restrict__ w1b,
                            const float* __restrict__ W2, u16* __restrict__ w2b,
                            const float* __restrict__ hidden, u16* __restrict__ hbf,
                            float* __restrict__ pooled) {
  const int bid = blockIdx.x, t = threadIdx.x;
  if (bid < 2304) {  // 8*768*3072 floats each = 1152 blocks * 16384
    const float* src = (bid < 1152) ? W1 : W2;
    u16* dst = (bid < 1152) ? w1b : w2b;
    const size_t base = (size_t)(bid < 1152 ? bid : bid - 1152) * 16384 + t * 4;
#pragma unroll
    for (int i = 0; i < 16; ++i) {
      const float4 v = *(const float4*)(src + base + (size_t)i * 1024);
      u16x4 o; o[0] = f2bf(v.x); o[1] = f2bf(v.y); o[2] = f2bf(v.z); o[3] = f2bf(v.w);
      *(u16x4*)(dst + base + (size_t)i * 1024) = o;
    }
    return;
  }
  if (t >= 192) return;  // convert role uses 192 lanes
  const int u = bid - 2304;                 // 512 units: 8 rows each
  const int b = u >> 6, chunk = u & 63;
  const size_t base = (size_t)b * 512 * 768 + (size_t)chunk * 8 * 768 + t * 4;
  float ax = 0.f, ay = 0.f, az = 0.f, aw = 0.f;
#pragma unroll
  for (int r = 0; r < 8; ++r) {
    const float4 v = *(const float4*)(hidden + base + r * 768);
    ax += v.x; ay += v.y; az += v.z; aw += v.w;
    u16x4 o; o[0] = f2bf(v.x); o[1] = f2bf(v.y); o[2] = f2bf(v.z); o[3] = f2bf(v.w);
    *(u16x4*)(hbf + base + r * 768) = o;
  }
  float* p = pooled + b * 768 + t * 4;
  atomicAdd(p + 0, ax); atomicAdd(p + 1, ay);
  atomicAdd(p + 2, az); atomicAdd(p + 3, aw);
}

// ---------- router finalize ----------
__global__ void router_final_kernel(const float* __restrict__ pooled, const float* __restrict__ Wg,
                                    float* __restrict__ logits_out, int* __restrict__ sel,
                                    float* __restrict__ wsel) {
  __shared__ float l8[64];
  const int tid = threadIdx.x;
  const int b = tid >> 5, r = tid & 31, e = r >> 2, q = r & 3;
  float p = 0.f;
  for (int h = q * 192; h < q * 192 + 192; ++h) p += pooled[b * 768 + h] * Wg[h * 8 + e];
  p += __shfl_xor(p, 1);
  p += __shfl_xor(p, 2);
  if (q == 0) {
    const float lg = p * (1.f / 512.f);
    l8[b * 8 + e] = lg;
    logits_out[b * 8 + e] = lg;
  }
  __syncthreads();
  if (tid < 8) {
    const int bb = tid;
    float mx = -1e30f;
    for (int i = 0; i < 8; ++i) mx = fmaxf(mx, l8[bb * 8 + i]);
    float w[8], ssum = 0.f;
    for (int i = 0; i < 8; ++i) { w[i] = __expf(l8[bb * 8 + i] - mx); ssum += w[i]; }
    for (int i = 0; i < 8; ++i) w[i] /= ssum;
    int i0 = 0;
    for (int i = 1; i < 8; ++i) if (w[i] > w[i0]) i0 = i;   // first-occurrence ties
    int i1 = (i0 == 0) ? 1 : 0;
    for (int i = 0; i < 8; ++i) if (i != i0 && w[i] > w[i1]) i1 = i;
    sel[bb * 2 + 0] = i0; sel[bb * 2 + 1] = i1;
    wsel[bb * 2 + 0] = w[i0]; wsel[bb * 2 + 1] = w[i1];
  }
}

// ---------- GEMM building blocks (128x128 tile, BK=64, 256 thr) ----------
// LDS: A single 8192 u16 + B single 8192 u16 = 32 KB -> 5 blocks/CU.
// Slot swizzle phys = logical ^ (row&7) on 16B slots (r0-proven reader).

// A: bf16 source, global_load_lds (4 dma instrs), source pre-swizzled.
DEV void stage_A(const u16* __restrict__ g, int ld, int row0, int k0,
                 u16* l, int tid) {
  const int crow = tid >> 3;                       // 0..31
  const int swz = ((tid & 7) ^ (crow & 7)) * 8;
  const int wbase = tid & ~63;
  const u16* gb = g + (size_t)(row0 + crow) * ld + k0 + swz;
#pragma unroll
  for (int i = 0; i < 4; ++i) {
    __builtin_amdgcn_global_load_lds(
        (const __attribute__((address_space(1))) void*)(gb + (size_t)i * 32 * ld),
        (__attribute__((address_space(3))) void*)(l + (i * 256 + wbase) * 8), 16, 0, 0);
  }
}

// B: native bf16 [k][n]. issue: 16 dword loads (2 cols x 8 k-rows x 2 groups),
// 128 B contiguous per 32-lane row segment.
DEV void bT_issue(const u16* __restrict__ src, int ld, int c0, int k0, int tid,
                  u32 (&v)[16]) {
  const int c = c0 + (tid & 31) * 2;
  const int r0 = k0 + (tid >> 5) * 8;
#pragma unroll
  for (int fh = 0; fh < 2; ++fh)
#pragma unroll
    for (int r = 0; r < 8; ++r)
      v[fh * 8 + r] = *(const u32*)(src + (size_t)(r0 + r) * ld + c + fh * 64);
}

// commit: pure bf16 bit-repack (no rounding) -> 4x ds_write_b128 swizzled.
// Write conflicts: 8 consecutive lanes -> 4 distinct slots = 2-way (free).
DEV void bT_commit(int tid, const u32 (&v)[16], u16* Bs) {
  const int s = tid >> 5;  // k-oct 0..7
#pragma unroll
  for (int fh = 0; fh < 2; ++fh) {
    const int fA = (tid & 31) * 2 + fh * 64;
    u32 lo[4], hi[4];
#pragma unroll
    for (int q = 0; q < 4; ++q) {
      const u32 a = v[fh * 8 + 2 * q], b = v[fh * 8 + 2 * q + 1];
      lo[q] = (a & 0xffffu) | (b << 16);
      hi[q] = (a >> 16) | (b & 0xffff0000u);
    }
    uint4 ox = {lo[0], lo[1], lo[2], lo[3]};
    uint4 oy = {hi[0], hi[1], hi[2], hi[3]};
    *(uint4*)(Bs + fA * 64 + ((s ^ (fA & 7)) * 8)) = ox;
    *(uint4*)(Bs + (fA + 1) * 64 + ((s ^ ((fA + 1) & 7)) * 8)) = oy;
  }
}

// One K-tile: 32 MFMA, setprio-wrapped. Reader identical to r0.
DEV void tile_compute(const u16* As, const u16* Bs, int wm, int wn, int mi, int kq,
                      f32x4 (&acc)[4][4]) {
  bf16x8 af[4][2], bfr[4][2];
#pragma unroll
  for (int mt = 0; mt < 4; ++mt) {
    const int row = wm + mt * 16 + mi;
#pragma unroll
    for (int ks = 0; ks < 2; ++ks) {
      const int slot = (ks * 4 + kq) ^ (row & 7);
      af[mt][ks] = *(const bf16x8*)(As + row * 64 + slot * 8);
    }
  }
#pragma unroll
  for (int nt = 0; nt < 4; ++nt) {
    const int row = wn + nt * 16 + mi;
#pragma unroll
    for (int ks = 0; ks < 2; ++ks) {
      const int slot = (ks * 4 + kq) ^ (row & 7);
      bfr[nt][ks] = *(const bf16x8*)(Bs + row * 64 + slot * 8);
    }
  }
  __builtin_amdgcn_s_setprio(1);
#pragma unroll
  for (int ks = 0; ks < 2; ++ks)
#pragma unroll
    for (int mt = 0; mt < 4; ++mt)
#pragma unroll
      for (int nt = 0; nt < 4; ++nt)
        acc[mt][nt] = __builtin_amdgcn_mfma_f32_16x16x32_bf16(af[mt][ks], bfr[nt][ks], acc[mt][nt], 0, 0, 0);
  __builtin_amdgcn_s_setprio(0);
}

// m97-style single-buffer loop. Per tile: barrier (all waves done reading
// smem) -> stage A(t) dma -> commit B(t) (its 16 loads have been in flight
// one full iteration; compiler waits vmcnt(4) for them, keeping A-dma out) ->
// issue B(t+1) -> vmcnt(16) retires A-dma only -> barrier -> 32 MFMA.
// Cross-block overlap (5/CU) hides the stage latency (m114).
#define GEMM_LOOP(NT, Aptr, Ald, Am0, Bptr, Bld, Bn0, KB)                         \
  bT_issue(Bptr, Bld, Bn0, (KB), tid, v);                                         \
  for (int t = 0; t < (NT); ++t) {                                                \
    __builtin_amdgcn_sched_barrier(0);                                            \
    __builtin_amdgcn_s_barrier();                                                 \
    __builtin_amdgcn_sched_barrier(0);                                            \
    stage_A(Aptr, Ald, Am0, (KB) + t * 64, As, tid);                              \
    bT_commit(tid, v, Bs);                                                        \
    if (t + 1 < (NT)) {                                                           \
      bT_issue(Bptr, Bld, Bn0, (KB) + (t + 1) * 64, tid, v);                      \
      asm volatile("s_waitcnt vmcnt(16) lgkmcnt(0)" ::: "memory");                \
    } else {                                                                      \
      asm volatile("s_waitcnt vmcnt(0) lgkmcnt(0)" ::: "memory");                 \
    }                                                                             \
    __builtin_amdgcn_sched_barrier(0);                                            \
    __builtin_amdgcn_s_barrier();                                                 \
    __builtin_amdgcn_sched_barrier(0);                                            \
    tile_compute(As, Bs, wm, wn, mi, kq, acc);                                    \
  }

// ---------- GEMM1: 1536 blocks, XCD x owns batch x's 2 pairs ----------
// xcd=bid&7, slot=bid>>3 (0..191), p=xcd*2+slot/96, tt=slot%96,
// m0=(tt/24)*128, n0=(tt%24)*128. B = w1b[e] native [768][3072] bf16.
__global__ __launch_bounds__(256, 2) void gemm1_kernel(
    const u16* __restrict__ hbf, const u16* __restrict__ w1b,
    const float* __restrict__ b1, u16* __restrict__ hbuf,
    const int* __restrict__ sel, const float* __restrict__ wsel) {
  __shared__ __align__(16) u16 smem[16384];  // 32 KB
  u16* As = smem;            // 8192 u16
  u16* Bs = smem + 8192;     // 8192 u16
  const int tid = threadIdx.x, bid = blockIdx.x;
  const int xcd = bid & 7, slot = bid >> 3;
  const int p = xcd * 2 + slot / 96;
  const int tt = slot % 96;
  const int m0 = (tt / 24) * 128, n0 = (tt % 24) * 128;
  const int b = p >> 1;
  const int e = sel[p];
  const float wgt = wsel[p];
  const u16* A = hbf + (size_t)b * 512 * 768;
  const u16* Bn = w1b + (size_t)e * 768 * 3072;   // native [h=768][f=3072]
  const int lane = tid & 63, wv = tid >> 6;
  const int wm = (wv >> 1) * 64, wn = (wv & 1) * 64;
  const int mi = lane & 15, kq = lane >> 4;

  f32x4 acc[4][4] = {};
  u32 v[16];
  GEMM_LOOP(12, A, 768, m0, Bn, 3072, n0, 0)

  // epilogue: C -> LDS ([128][66] per 64-col half) -> coalesced u16x8 stores
  const float* b1e = b1 + e * 3072;
  u16* C = hbuf + (size_t)p * 512 * 3072;
  u16* cs = smem;  // 128*66 = 8448 u16 <= 16384
#pragma unroll
  for (int half = 0; half < 2; ++half) {
    __syncthreads();
    if ((wn >> 6) == half) {
#pragma unroll
      for (int nt = 0; nt < 4; ++nt) {
        const int colL = nt * 16 + mi;                 // 0..63 within half
        const float bias = b1e[n0 + half * 64 + colL];
#pragma unroll
        for (int mt = 0; mt < 4; ++mt) {
#pragma unroll
          for (int r = 0; r < 4; ++r) {
            const int row = wm + mt * 16 + kq * 4 + r; // C/D: col=lane&15, row=quad*4+reg
            const float x = acc[mt][nt][r] + bias;
            const float g = 0.5f * x * (1.f + erff(x * 0.70710678118654752f));  // exact GELU
            cs[row * 66 + colL] = f2bf(wgt * g);
          }
        }
      }
    }
    __syncthreads();
#pragma unroll
    for (int i = 0; i < 4; ++i) {
      const int idx = i * 256 + tid;
      const int row = idx >> 3, c8 = (idx & 7) * 8;
      *(u16x8*)(C + (size_t)(m0 + row) * 3072 + n0 + half * 64 + c8) =
          *(const u16x8*)(cs + row * 66 + c8);
    }
  }
}

// ---------- GEMM2: split-K x4, 768 blocks, fp32 atomics ----------
// xcd=bid&7 (= batch), slot=bid>>3 (0..95), ks=slot/24, tt=slot%24,
// m0=(tt/6)*128, n0=(tt%6)*128. kslot=ks>>1 expert, kbase=(ks&1)*1536.
// B = w2b[e] native [3072][768] bf16. ks==0 adds weighted bias.
__global__ __launch_bounds__(256, 2) void gemm2_kernel(
    const u16* __restrict__ hbuf, const u16* __restrict__ w2b,
    const float* __restrict__ b2, float* __restrict__ out,
    const int* __restrict__ sel, const float* __restrict__ wsel) {
  __shared__ __align__(16) u16 smem[16384];  // 32 KB
  u16* As = smem;
  u16* Bs = smem + 8192;
  const int tid = threadIdx.x, bid = blockIdx.x;
  const int b = bid & 7, slot = bid >> 3;
  const int ks = slot / 24, tt = slot % 24;
  const int m0 = (tt / 6) * 128, n0 = (tt % 6) * 128;
  const int kslot = ks >> 1;
  const int e = sel[b * 2 + kslot];
  const u16* A = hbuf + (size_t)(b * 2 + kslot) * 512 * 3072;
  const u16* Bn = w2b + (size_t)e * 3072 * 768;   // native [f=3072][h=768]
  const int kbase = (ks & 1) * 1536;
  const int lane = tid & 63, wv = tid >> 6;
  const int wm = (wv >> 1) * 64, wn = (wv & 1) * 64;
  const int mi = lane & 15, kq = lane >> 4;

  f32x4 acc[4][4] = {};
  u32 v[16];
  GEMM_LOOP(24, A, 3072, m0, Bn, 768, n0, kbase)

  float* C = out + (size_t)b * 512 * 768;
  const float w0 = wsel[b * 2 + 0], w1 = wsel[b * 2 + 1];
  const float* b2e0 = b2 + sel[b * 2 + 0] * 768;
  const float* b2e1 = b2 + sel[b * 2 + 1] * 768;
#pragma unroll
  for (int nt = 0; nt < 4; ++nt) {
    const int col = n0 + wn + nt * 16 + mi;
    const float bias = (ks == 0) ? (w0 * b2e0[col] + w1 * b2e1[col]) : 0.f;
#pragma unroll
    for (int mt = 0; mt < 4; ++mt) {
#pragma unroll
      for (int r = 0; r < 4; ++r) {
        const int row = m0 + wm + mt * 16 + kq * 4 + r;
        atomicAdd(&C[(size_t)row * 768 + col], acc[mt][nt][r] + bias);
      }
    }
  }
}

extern "C" void kernel_launch(void* const* d_in, const int* in_sizes, int n_in,
                              void* d_out, int out_size, void* d_ws, size_t ws_size,
                              hipStream_t stream) {
  const float* hidden = (const float*)d_in[0];  // [8,512,768] fp32
  const float* Wg     = (const float*)d_in[1];  // [768,8]
  const float* W1     = (const float*)d_in[2];  // [8,768,3072]
  const float* b1     = (const float*)d_in[3];  // [8,3072]
  const float* W2     = (const float*)d_in[4];  // [8,3072,768]
  const float* b2     = (const float*)d_in[5];  // [8,768]
  float* out = (float*)d_out;                   // [8,512,768] ++ logits [8,8]

  char* ws = (char*)d_ws;
  int*   sel    = (int*)ws;
  float* wsel   = (float*)(ws + 64);
  float* pooled = (float*)(ws + 128);
  u16* hbf  = (u16*)(ws + 32768);               // 6.29 MB bf16 hidden
  u16* w1b  = hbf + (size_t)8 * 512 * 768;      // 37.75 MB bf16 W1 (native)
  u16* w2b  = w1b + (size_t)8 * 768 * 3072;     // 37.75 MB bf16 W2 (native)
  u16* hbuf = w2b + (size_t)8 * 768 * 3072;     // 50.33 MB bf16 activations

  float* logits_out = out + (size_t)8 * 512 * 768;

  hipMemsetAsync(ws, 0, 32768, stream);                  // sel/wsel/pooled
  hipMemsetAsync(out, 0, (size_t)out_size * 4, stream);  // atomic accum base
  prep_kernel<<<2816, 256, 0, stream>>>(W1, w1b, W2, w2b, hidden, hbf, pooled);
  router_final_kernel<<<1, 256, 0, stream>>>(pooled, Wg, logits_out, sel, wsel);
  gemm1_kernel<<<1536, 256, 0, stream>>>(hbf, w1b, b1, hbuf, sel, wsel);
  gemm2_kernel<<<768, 256, 0, stream>>>(hbuf, w2b, b2, out, sel, wsel);
}

// Round 11
// 357.356 us; speedup vs baseline: 1.7620x; 1.0174x over previous
//
#include <hip/hip_runtime.h>

typedef unsigned short u16;
typedef unsigned int u32;
typedef __attribute__((ext_vector_type(8))) short bf16x8;
typedef __attribute__((ext_vector_type(4))) float f32x4;
typedef __attribute__((ext_vector_type(8))) u16 u16x8;
typedef __attribute__((ext_vector_type(4))) u16 u16x4;

#define DEV __device__ __forceinline__

DEV u16 f2bf(float f) {
  u32 x = __float_as_uint(f);
  return (u16)((x + 0x7fffu + ((x >> 16) & 1u)) >> 16);  // RNE
}

// B=8 S=512 H=768 E=8 F=3072 K=2. fp32 I/O; bf16 MFMA internals.
// r14 (resubmit after broker timeout): eliminate the in-loop B repack (r13:
// 16 flat loads + ~40 VALU pack + 4 ds_write_b128 with 8-way write conflicts
// = the 38% VALUBusy + 3.1M conflicts). prep pre-transposes weights to bf16
// (w1t [3072][768], w2t [768][3072], r0-proven LDS transpose tiles); both
// GEMMs stage A AND B via global_load_lds (8 dma/tile, zero VALU staging) in
// the m97 32KB single-buffer loop (5 blocks/CU). Keeps: XCD mapping,
// LDS-bounced coalesced gemm1 stores, split-K x4 gemm2.

// ---------- 128x64 tile transpose: fp32 src -> bf16 dst (256 thr) ----------
DEV void transpose_tile(const float* __restrict__ src, u16* __restrict__ dst,
                        int R, int C, int r0, int c0, int t, u16* tile /*128*68*/) {
#pragma unroll
  for (int i = 0; i < 8; ++i) {
    const int idx = i * 256 + t;
    const int row = idx >> 4, c4 = (idx & 15) * 4;
    const float4 v = *(const float4*)(src + (size_t)(r0 + row) * C + c0 + c4);
    u16x4 o; o[0] = f2bf(v.x); o[1] = f2bf(v.y); o[2] = f2bf(v.z); o[3] = f2bf(v.w);
    *(u16x4*)(tile + row * 68 + c4) = o;
  }
  __syncthreads();
#pragma unroll
  for (int i = 0; i < 4; ++i) {
    const int widx = i * 256 + t;
    const int c = widx >> 4, r8 = (widx & 15) * 8;
    u16x8 o;
#pragma unroll
    for (int j = 0; j < 8; ++j) o[j] = tile[(r8 + j) * 68 + c];
    *(u16x8*)(dst + (size_t)(c0 + c) * R + r0 + r8) = o;
  }
}

// ---------- prep: [0,2304) W1^T; [2304,4608) W2^T; [4608,5120) hidden+pool ----
__global__ void prep_kernel(const float* __restrict__ W1, u16* __restrict__ w1t,
                            const float* __restrict__ W2, u16* __restrict__ w2t,
                            const float* __restrict__ hidden, u16* __restrict__ hbf,
                            float* __restrict__ pooled) {
  __shared__ __align__(16) u16 smem[128 * 68];
  const int bid = blockIdx.x, t = threadIdx.x;
  if (bid < 2304) {  // W1 [768,3072] -> [3072,768]: 6x48 tiles/expert
    const int e = bid / 288, rem = bid % 288;
    const int r0 = (rem / 48) * 128, c0 = (rem % 48) * 64;
    transpose_tile(W1 + (size_t)e * 768 * 3072, w1t + (size_t)e * 768 * 3072,
                   768, 3072, r0, c0, t, smem);
    return;
  }
  if (bid < 4608) {  // W2 [3072,768] -> [768,3072]: 24x12 tiles/expert
    const int bb = bid - 2304;
    const int e = bb / 288, rem = bb % 288;
    const int r0 = (rem / 12) * 128, c0 = (rem % 12) * 64;
    transpose_tile(W2 + (size_t)e * 3072 * 768, w2t + (size_t)e * 3072 * 768,
                   3072, 768, r0, c0, t, smem);
    return;
  }
  if (t >= 192) return;  // convert role uses 192 lanes
  const int u = bid - 4608;                 // 512 units: 8 rows each
  const int b = u >> 6, chunk = u & 63;
  const size_t base = (size_t)b * 512 * 768 + (size_t)chunk * 8 * 768 + t * 4;
  float ax = 0.f, ay = 0.f, az = 0.f, aw = 0.f;
#pragma unroll
  for (int r = 0; r < 8; ++r) {
    const float4 v = *(const float4*)(hidden + base + r * 768);
    ax += v.x; ay += v.y; az += v.z; aw += v.w;
    u16x4 o; o[0] = f2bf(v.x); o[1] = f2bf(v.y); o[2] = f2bf(v.z); o[3] = f2bf(v.w);
    *(u16x4*)(hbf + base + r * 768) = o;
  }
  float* p = pooled + b * 768 + t * 4;
  atomicAdd(p + 0, ax); atomicAdd(p + 1, ay);
  atomicAdd(p + 2, az); atomicAdd(p + 3, aw);
}

// ---------- router finalize ----------
__global__ void router_final_kernel(const float* __restrict__ pooled, const float* __restrict__ Wg,
                                    float* __restrict__ logits_out, int* __restrict__ sel,
                                    float* __restrict__ wsel) {
  __shared__ float l8[64];
  const int tid = threadIdx.x;
  const int b = tid >> 5, r = tid & 31, e = r >> 2, q = r & 3;
  float p = 0.f;
  for (int h = q * 192; h < q * 192 + 192; ++h) p += pooled[b * 768 + h] * Wg[h * 8 + e];
  p += __shfl_xor(p, 1);
  p += __shfl_xor(p, 2);
  if (q == 0) {
    const float lg = p * (1.f / 512.f);
    l8[b * 8 + e] = lg;
    logits_out[b * 8 + e] = lg;
  }
  __syncthreads();
  if (tid < 8) {
    const int bb = tid;
    float mx = -1e30f;
    for (int i = 0; i < 8; ++i) mx = fmaxf(mx, l8[bb * 8 + i]);
    float w[8], ssum = 0.f;
    for (int i = 0; i < 8; ++i) { w[i] = __expf(l8[bb * 8 + i] - mx); ssum += w[i]; }
    for (int i = 0; i < 8; ++i) w[i] /= ssum;
    int i0 = 0;
    for (int i = 1; i < 8; ++i) if (w[i] > w[i0]) i0 = i;   // first-occurrence ties
    int i1 = (i0 == 0) ? 1 : 0;
    for (int i = 0; i < 8; ++i) if (i != i0 && w[i] > w[i1]) i1 = i;
    sel[bb * 2 + 0] = i0; sel[bb * 2 + 1] = i1;
    wsel[bb * 2 + 0] = w[i0]; wsel[bb * 2 + 1] = w[i1];
  }
}

// ---------- GEMM building blocks (128x128 tile, BK=64, 256 thr) ----------
// LDS: A 8192 u16 + B 8192 u16 = 32 KB single-buffer -> 5 blocks/CU.
// Slot swizzle phys = logical ^ (row&7) on 16B slots; DMA source
// pre-swizzled, reader un-swizzles (r0/r13-proven pair).

DEV void stage_tile(const u16* __restrict__ g, int ld, int row0, int k0,
                    u16* l, int tid) {
  const int crow = tid >> 3;                       // 0..31
  const int swz = ((tid & 7) ^ (crow & 7)) * 8;
  const int wbase = tid & ~63;
  const u16* gb = g + (size_t)(row0 + crow) * ld + k0 + swz;
#pragma unroll
  for (int i = 0; i < 4; ++i) {
    __builtin_amdgcn_global_load_lds(
        (const __attribute__((address_space(1))) void*)(gb + (size_t)i * 32 * ld),
        (__attribute__((address_space(3))) void*)(l + (i * 256 + wbase) * 8), 16, 0, 0);
  }
}

// One K-tile: 32 MFMA, setprio-wrapped. Reader identical to r0.
DEV void tile_compute(const u16* As, const u16* Bs, int wm, int wn, int mi, int kq,
                      f32x4 (&acc)[4][4]) {
  bf16x8 af[4][2], bfr[4][2];
#pragma unroll
  for (int mt = 0; mt < 4; ++mt) {
    const int row = wm + mt * 16 + mi;
#pragma unroll
    for (int ks = 0; ks < 2; ++ks) {
      const int slot = (ks * 4 + kq) ^ (row & 7);
      af[mt][ks] = *(const bf16x8*)(As + row * 64 + slot * 8);
    }
  }
#pragma unroll
  for (int nt = 0; nt < 4; ++nt) {
    const int row = wn + nt * 16 + mi;
#pragma unroll
    for (int ks = 0; ks < 2; ++ks) {
      const int slot = (ks * 4 + kq) ^ (row & 7);
      bfr[nt][ks] = *(const bf16x8*)(Bs + row * 64 + slot * 8);
    }
  }
  __builtin_amdgcn_s_setprio(1);
#pragma unroll
  for (int ks = 0; ks < 2; ++ks)
#pragma unroll
    for (int mt = 0; mt < 4; ++mt)
#pragma unroll
      for (int nt = 0; nt < 4; ++nt)
        acc[mt][nt] = __builtin_amdgcn_mfma_f32_16x16x32_bf16(af[mt][ks], bfr[nt][ks], acc[mt][nt], 0, 0, 0);
  __builtin_amdgcn_s_setprio(0);
}

// m97 single-buffer loop: barrier (waves done reading) -> 8 dma (A+B) ->
// vmcnt(0) -> barrier -> 32 MFMA. Both dma streams in flight together, so
// the drain exposes ~max(A,B) latency; 5 blocks/CU hide it (m114).
#define GEMM_LOOP(NT, Aptr, Ald, Am0, Bptr, Bld, Bn0, KB)                         \
  for (int t = 0; t < (NT); ++t) {                                                \
    __builtin_amdgcn_sched_barrier(0);                                            \
    __builtin_amdgcn_s_barrier();                                                 \
    __builtin_amdgcn_sched_barrier(0);                                            \
    stage_tile(Aptr, Ald, Am0, (KB) + t * 64, As, tid);                           \
    stage_tile(Bptr, Bld, Bn0, (KB) + t * 64, Bs, tid);                           \
    asm volatile("s_waitcnt vmcnt(0) lgkmcnt(0)" ::: "memory");                   \
    __builtin_amdgcn_sched_barrier(0);                                            \
    __builtin_amdgcn_s_barrier();                                                 \
    __builtin_amdgcn_sched_barrier(0);                                            \
    tile_compute(As, Bs, wm, wn, mi, kq, acc);                                    \
  }

// ---------- GEMM1: 1536 blocks, XCD x owns batch x's 2 pairs ----------
// xcd=bid&7, slot=bid>>3 (0..191), p=xcd*2+slot/96, tt=slot%96,
// m0=(tt/24)*128, n0=(tt%24)*128. B = w1t[e] [3072][768] bf16 (transposed).
__global__ __launch_bounds__(256, 2) void gemm1_kernel(
    const u16* __restrict__ hbf, const u16* __restrict__ w1t,
    const float* __restrict__ b1, u16* __restrict__ hbuf,
    const int* __restrict__ sel, const float* __restrict__ wsel) {
  __shared__ __align__(16) u16 smem[16384];  // 32 KB
  u16* As = smem;            // 8192 u16
  u16* Bs = smem + 8192;     // 8192 u16
  const int tid = threadIdx.x, bid = blockIdx.x;
  const int xcd = bid & 7, slot = bid >> 3;
  const int p = xcd * 2 + slot / 96;
  const int tt = slot % 96;
  const int m0 = (tt / 24) * 128, n0 = (tt % 24) * 128;
  const int b = p >> 1;
  const int e = sel[p];
  const float wgt = wsel[p];
  const u16* A = hbf + (size_t)b * 512 * 768;
  const u16* Bt = w1t + (size_t)e * 768 * 3072;   // [f=3072][h=768]
  const int lane = tid & 63, wv = tid >> 6;
  const int wm = (wv >> 1) * 64, wn = (wv & 1) * 64;
  const int mi = lane & 15, kq = lane >> 4;

  f32x4 acc[4][4] = {};
  GEMM_LOOP(12, A, 768, m0, Bt, 768, n0, 0)

  // epilogue: C -> LDS ([128][66] per 64-col half) -> coalesced u16x8 stores
  const float* b1e = b1 + e * 3072;
  u16* C = hbuf + (size_t)p * 512 * 3072;
  u16* cs = smem;  // 128*66 = 8448 u16 <= 16384
#pragma unroll
  for (int half = 0; half < 2; ++half) {
    __syncthreads();
    if ((wn >> 6) == half) {
#pragma unroll
      for (int nt = 0; nt < 4; ++nt) {
        const int colL = nt * 16 + mi;                 // 0..63 within half
        const float bias = b1e[n0 + half * 64 + colL];
#pragma unroll
        for (int mt = 0; mt < 4; ++mt) {
#pragma unroll
          for (int r = 0; r < 4; ++r) {
            const int row = wm + mt * 16 + kq * 4 + r; // C/D: col=lane&15, row=quad*4+reg
            const float x = acc[mt][nt][r] + bias;
            const float g = 0.5f * x * (1.f + erff(x * 0.70710678118654752f));  // exact GELU
            cs[row * 66 + colL] = f2bf(wgt * g);
          }
        }
      }
    }
    __syncthreads();
#pragma unroll
    for (int i = 0; i < 4; ++i) {
      const int idx = i * 256 + tid;
      const int row = idx >> 3, c8 = (idx & 7) * 8;
      *(u16x8*)(C + (size_t)(m0 + row) * 3072 + n0 + half * 64 + c8) =
          *(const u16x8*)(cs + row * 66 + c8);
    }
  }
}

// ---------- GEMM2: split-K x4, 768 blocks, fp32 atomics ----------
// xcd=bid&7 (= batch), slot=bid>>3 (0..95), ks=slot/24, tt=slot%24,
// m0=(tt/6)*128, n0=(tt%6)*128. kslot=ks>>1 expert, kbase=(ks&1)*1536.
// B = w2t[e] [768][3072] bf16 (transposed). ks==0 adds weighted bias.
__global__ __launch_bounds__(256, 2) void gemm2_kernel(
    const u16* __restrict__ hbuf, const u16* __restrict__ w2t,
    const float* __restrict__ b2, float* __restrict__ out,
    const int* __restrict__ sel, const float* __restrict__ wsel) {
  __shared__ __align__(16) u16 smem[16384];  // 32 KB
  u16* As = smem;
  u16* Bs = smem + 8192;
  const int tid = threadIdx.x, bid = blockIdx.x;
  const int b = bid & 7, slot = bid >> 3;
  const int ks = slot / 24, tt = slot % 24;
  const int m0 = (tt / 6) * 128, n0 = (tt % 6) * 128;
  const int kslot = ks >> 1;
  const int e = sel[b * 2 + kslot];
  const u16* A = hbuf + (size_t)(b * 2 + kslot) * 512 * 3072;
  const u16* Bt = w2t + (size_t)e * 768 * 3072;   // [h=768][f=3072]
  const int kbase = (ks & 1) * 1536;
  const int lane = tid & 63, wv = tid >> 6;
  const int wm = (wv >> 1) * 64, wn = (wv & 1) * 64;
  const int mi = lane & 15, kq = lane >> 4;

  f32x4 acc[4][4] = {};
  GEMM_LOOP(24, A, 3072, m0, Bt, 3072, n0, kbase)

  float* C = out + (size_t)b * 512 * 768;
  const float w0 = wsel[b * 2 + 0], w1 = wsel[b * 2 + 1];
  const float* b2e0 = b2 + sel[b * 2 + 0] * 768;
  const float* b2e1 = b2 + sel[b * 2 + 1] * 768;
#pragma unroll
  for (int nt = 0; nt < 4; ++nt) {
    const int col = n0 + wn + nt * 16 + mi;
    const float bias = (ks == 0) ? (w0 * b2e0[col] + w1 * b2e1[col]) : 0.f;
#pragma unroll
    for (int mt = 0; mt < 4; ++mt) {
#pragma unroll
      for (int r = 0; r < 4; ++r) {
        const int row = m0 + wm + mt * 16 + kq * 4 + r;
        atomicAdd(&C[(size_t)row * 768 + col], acc[mt][nt][r] + bias);
      }
    }
  }
}

extern "C" void kernel_launch(void* const* d_in, const int* in_sizes, int n_in,
                              void* d_out, int out_size, void* d_ws, size_t ws_size,
                              hipStream_t stream) {
  const float* hidden = (const float*)d_in[0];  // [8,512,768] fp32
  const float* Wg     = (const float*)d_in[1];  // [768,8]
  const float* W1     = (const float*)d_in[2];  // [8,768,3072]
  const float* b1     = (const float*)d_in[3];  // [8,3072]
  const float* W2     = (const float*)d_in[4];  // [8,3072,768]
  const float* b2     = (const float*)d_in[5];  // [8,768]
  float* out = (float*)d_out;                   // [8,512,768] ++ logits [8,8]

  char* ws = (char*)d_ws;
  int*   sel    = (int*)ws;
  float* wsel   = (float*)(ws + 64);
  float* pooled = (float*)(ws + 128);
  u16* hbf  = (u16*)(ws + 32768);               // 6.29 MB bf16 hidden
  u16* w1t  = hbf + (size_t)8 * 512 * 768;      // 37.75 MB bf16 W1^T [3072][768]
  u16* w2t  = w1t + (size_t)8 * 768 * 3072;     // 37.75 MB bf16 W2^T [768][3072]
  u16* hbuf = w2t + (size_t)8 * 768 * 3072;     // 50.33 MB bf16 activations

  float* logits_out = out + (size_t)8 * 512 * 768;

  hipMemsetAsync(ws, 0, 32768, stream);                  // sel/wsel/pooled
  hipMemsetAsync(out, 0, (size_t)out_size * 4, stream);  // atomic accum base
  prep_kernel<<<5120, 256, 0, stream>>>(W1, w1t, W2, w2t, hidden, hbf, pooled);
  router_final_kernel<<<1, 256, 0, stream>>>(pooled, Wg, logits_out, sel, wsel);
  gemm1_kernel<<<1536, 256, 0, stream>>>(hbf, w1t, b1, hbuf, sel, wsel);
  gemm2_kernel<<<768, 256, 0, stream>>>(hbuf, w2t, b2, out, sel, wsel);
}

// Round 12
// 345.574 us; speedup vs baseline: 1.8221x; 1.0341x over previous
//
#include <hip/hip_runtime.h>

typedef unsigned short u16;
typedef unsigned int u32;
typedef __attribute__((ext_vector_type(8))) short bf16x8;
typedef __attribute__((ext_vector_type(4))) float f32x4;
typedef __attribute__((ext_vector_type(8))) u16 u16x8;
typedef __attribute__((ext_vector_type(4))) u16 u16x4;

#define DEV __device__ __forceinline__

DEV u16 f2bf(float f) {
  u32 x = __float_as_uint(f);
  return (u16)((x + 0x7fffu + ((x >> 16) & 1u)) >> 16);  // RNE
}

// B=8 S=512 H=768 E=8 F=3072 K=2. fp32 I/O; bf16 MFMA internals.
// r15: prep was 80us @ 26% HBM with 8.2M LDS conflicts — transpose column
// read at stride 68 is an 8-way conflict (lane step 16 mod 32 -> 2 banks).
// Fix: stride 65 (odd -> 8 banks -> 2-way = free), scalar u16 writes.
// W2^T moves back into gemm1's grid (r0-proven overlap of HBM-bound
// transpose blocks with latency-bound GEMM blocks). GEMM loops = r14
// (pure global_load_lds staging, m97 32KB single-buffer, 5 blocks/CU).

#define TS 65  // transpose tile LDS stride (odd => conflict-free column read)

// ---------- 128x64 tile transpose: fp32 src -> bf16 dst (256 thr) ----------
DEV void transpose_tile(const float* __restrict__ src, u16* __restrict__ dst,
                        int R, int C, int r0, int c0, int t, u16* tile /*128*TS*/) {
#pragma unroll
  for (int i = 0; i < 8; ++i) {
    const int idx = i * 256 + t;
    const int row = idx >> 4, c4 = (idx & 15) * 4;
    const float4 v = *(const float4*)(src + (size_t)(r0 + row) * C + c0 + c4);
    u16* w = tile + row * TS + c4;
    w[0] = f2bf(v.x); w[1] = f2bf(v.y); w[2] = f2bf(v.z); w[3] = f2bf(v.w);
  }
  __syncthreads();
#pragma unroll
  for (int i = 0; i < 4; ++i) {
    const int widx = i * 256 + t;
    const int c = widx >> 4, r8 = (widx & 15) * 8;
    u16x8 o;
#pragma unroll
    for (int j = 0; j < 8; ++j) o[j] = tile[(r8 + j) * TS + c];
    *(u16x8*)(dst + (size_t)(c0 + c) * R + r0 + r8) = o;
  }
}

// ---------- prep: [0,2304) W1^T tiles; [2304,2816) hidden convert+pool ----
__global__ void prep_kernel(const float* __restrict__ W1, u16* __restrict__ w1t,
                            const float* __restrict__ hidden, u16* __restrict__ hbf,
                            float* __restrict__ pooled) {
  __shared__ __align__(16) u16 smem[128 * TS];
  const int bid = blockIdx.x, t = threadIdx.x;
  if (bid < 2304) {  // W1 [768,3072] -> [3072,768]: 6x48 tiles/expert
    const int e = bid / 288, rem = bid % 288;
    const int r0 = (rem / 48) * 128, c0 = (rem % 48) * 64;
    transpose_tile(W1 + (size_t)e * 768 * 3072, w1t + (size_t)e * 768 * 3072,
                   768, 3072, r0, c0, t, smem);
    return;
  }
  if (t >= 192) return;  // convert role uses 192 lanes
  const int u = bid - 2304;                 // 512 units: 8 rows each
  const int b = u >> 6, chunk = u & 63;
  const size_t base = (size_t)b * 512 * 768 + (size_t)chunk * 8 * 768 + t * 4;
  float ax = 0.f, ay = 0.f, az = 0.f, aw = 0.f;
#pragma unroll
  for (int r = 0; r < 8; ++r) {
    const float4 v = *(const float4*)(hidden + base + r * 768);
    ax += v.x; ay += v.y; az += v.z; aw += v.w;
    u16x4 o; o[0] = f2bf(v.x); o[1] = f2bf(v.y); o[2] = f2bf(v.z); o[3] = f2bf(v.w);
    *(u16x4*)(hbf + base + r * 768) = o;
  }
  float* p = pooled + b * 768 + t * 4;
  atomicAdd(p + 0, ax); atomicAdd(p + 1, ay);
  atomicAdd(p + 2, az); atomicAdd(p + 3, aw);
}

// ---------- router finalize ----------
__global__ void router_final_kernel(const float* __restrict__ pooled, const float* __restrict__ Wg,
                                    float* __restrict__ logits_out, int* __restrict__ sel,
                                    float* __restrict__ wsel) {
  __shared__ float l8[64];
  const int tid = threadIdx.x;
  const int b = tid >> 5, r = tid & 31, e = r >> 2, q = r & 3;
  float p = 0.f;
  for (int h = q * 192; h < q * 192 + 192; ++h) p += pooled[b * 768 + h] * Wg[h * 8 + e];
  p += __shfl_xor(p, 1);
  p += __shfl_xor(p, 2);
  if (q == 0) {
    const float lg = p * (1.f / 512.f);
    l8[b * 8 + e] = lg;
    logits_out[b * 8 + e] = lg;
  }
  __syncthreads();
  if (tid < 8) {
    const int bb = tid;
    float mx = -1e30f;
    for (int i = 0; i < 8; ++i) mx = fmaxf(mx, l8[bb * 8 + i]);
    float w[8], ssum = 0.f;
    for (int i = 0; i < 8; ++i) { w[i] = __expf(l8[bb * 8 + i] - mx); ssum += w[i]; }
    for (int i = 0; i < 8; ++i) w[i] /= ssum;
    int i0 = 0;
    for (int i = 1; i < 8; ++i) if (w[i] > w[i0]) i0 = i;   // first-occurrence ties
    int i1 = (i0 == 0) ? 1 : 0;
    for (int i = 0; i < 8; ++i) if (i != i0 && w[i] > w[i1]) i1 = i;
    sel[bb * 2 + 0] = i0; sel[bb * 2 + 1] = i1;
    wsel[bb * 2 + 0] = w[i0]; wsel[bb * 2 + 1] = w[i1];
  }
}

// ---------- GEMM building blocks (128x128 tile, BK=64, 256 thr) ----------
// LDS: A 8192 u16 + B 8192 u16 = 32 KB single-buffer -> 5 blocks/CU.
// Slot swizzle phys = logical ^ (row&7) on 16B slots; DMA source
// pre-swizzled, reader un-swizzles (r0/r13-proven pair).

DEV void stage_tile(const u16* __restrict__ g, int ld, int row0, int k0,
                    u16* l, int tid) {
  const int crow = tid >> 3;                       // 0..31
  const int swz = ((tid & 7) ^ (crow & 7)) * 8;
  const int wbase = tid & ~63;
  const u16* gb = g + (size_t)(row0 + crow) * ld + k0 + swz;
#pragma unroll
  for (int i = 0; i < 4; ++i) {
    __builtin_amdgcn_global_load_lds(
        (const __attribute__((address_space(1))) void*)(gb + (size_t)i * 32 * ld),
        (__attribute__((address_space(3))) void*)(l + (i * 256 + wbase) * 8), 16, 0, 0);
  }
}

// One K-tile: 32 MFMA, setprio-wrapped. Reader identical to r0.
DEV void tile_compute(const u16* As, const u16* Bs, int wm, int wn, int mi, int kq,
                      f32x4 (&acc)[4][4]) {
  bf16x8 af[4][2], bfr[4][2];
#pragma unroll
  for (int mt = 0; mt < 4; ++mt) {
    const int row = wm + mt * 16 + mi;
#pragma unroll
    for (int ks = 0; ks < 2; ++ks) {
      const int slot = (ks * 4 + kq) ^ (row & 7);
      af[mt][ks] = *(const bf16x8*)(As + row * 64 + slot * 8);
    }
  }
#pragma unroll
  for (int nt = 0; nt < 4; ++nt) {
    const int row = wn + nt * 16 + mi;
#pragma unroll
    for (int ks = 0; ks < 2; ++ks) {
      const int slot = (ks * 4 + kq) ^ (row & 7);
      bfr[nt][ks] = *(const bf16x8*)(Bs + row * 64 + slot * 8);
    }
  }
  __builtin_amdgcn_s_setprio(1);
#pragma unroll
  for (int ks = 0; ks < 2; ++ks)
#pragma unroll
    for (int mt = 0; mt < 4; ++mt)
#pragma unroll
      for (int nt = 0; nt < 4; ++nt)
        acc[mt][nt] = __builtin_amdgcn_mfma_f32_16x16x32_bf16(af[mt][ks], bfr[nt][ks], acc[mt][nt], 0, 0, 0);
  __builtin_amdgcn_s_setprio(0);
}

// m97 single-buffer loop: barrier (waves done reading) -> 8 dma (A+B) ->
// vmcnt(0) -> barrier -> 32 MFMA. 5 blocks/CU hide the drain (m114).
#define GEMM_LOOP(NT, Aptr, Ald, Am0, Bptr, Bld, Bn0, KB)                         \
  for (int t = 0; t < (NT); ++t) {                                                \
    __builtin_amdgcn_sched_barrier(0);                                            \
    __builtin_amdgcn_s_barrier();                                                 \
    __builtin_amdgcn_sched_barrier(0);                                            \
    stage_tile(Aptr, Ald, Am0, (KB) + t * 64, As, tid);                           \
    stage_tile(Bptr, Bld, Bn0, (KB) + t * 64, Bs, tid);                           \
    asm volatile("s_waitcnt vmcnt(0) lgkmcnt(0)" ::: "memory");                   \
    __builtin_amdgcn_sched_barrier(0);                                            \
    __builtin_amdgcn_s_barrier();                                                 \
    __builtin_amdgcn_sched_barrier(0);                                            \
    tile_compute(As, Bs, wm, wn, mi, kq, acc);                                    \
  }

// ---------- GEMM1 (+fused W2^T when bid<nT) ----------
// gemm part: xcd=bid&7, slot=bid>>3 (0..191), p=xcd*2+slot/96, tt=slot%96,
// m0=(tt/24)*128, n0=(tt%24)*128. B = w1t[e] [3072][768] bf16 (transposed).
__global__ __launch_bounds__(256, 2) void gemm1_kernel(
    const u16* __restrict__ hbf, const u16* __restrict__ w1t,
    const float* __restrict__ b1, u16* __restrict__ hbuf,
    const int* __restrict__ sel, const float* __restrict__ wsel,
    const float* __restrict__ W2, u16* __restrict__ w2t, int nT) {
  __shared__ __align__(16) u16 smem[16384];  // 32 KB
  const int tid = threadIdx.x;
  int bid = blockIdx.x;
  if (bid < nT) {  // W2 [3072,768] -> [768,3072]: 24x12 tiles/expert
    const int e = bid / 288, rem = bid % 288;
    const int r0 = (rem / 12) * 128, c0 = (rem % 12) * 64;
    transpose_tile(W2 + (size_t)e * 3072 * 768, w2t + (size_t)e * 3072 * 768,
                   3072, 768, r0, c0, tid, smem);
    return;
  }
  bid -= nT;
  u16* As = smem;            // 8192 u16
  u16* Bs = smem + 8192;     // 8192 u16
  const int xcd = bid & 7, slot = bid >> 3;
  const int p = xcd * 2 + slot / 96;
  const int tt = slot % 96;
  const int m0 = (tt / 24) * 128, n0 = (tt % 24) * 128;
  const int b = p >> 1;
  const int e = sel[p];
  const float wgt = wsel[p];
  const u16* A = hbf + (size_t)b * 512 * 768;
  const u16* Bt = w1t + (size_t)e * 768 * 3072;   // [f=3072][h=768]
  const int lane = tid & 63, wv = tid >> 6;
  const int wm = (wv >> 1) * 64, wn = (wv & 1) * 64;
  const int mi = lane & 15, kq = lane >> 4;

  f32x4 acc[4][4] = {};
  GEMM_LOOP(12, A, 768, m0, Bt, 768, n0, 0)

  // epilogue: C -> LDS ([128][66] per 64-col half) -> coalesced u16x8 stores
  const float* b1e = b1 + e * 3072;
  u16* C = hbuf + (size_t)p * 512 * 3072;
  u16* cs = smem;  // 128*66 = 8448 u16 <= 16384
#pragma unroll
  for (int half = 0; half < 2; ++half) {
    __syncthreads();
    if ((wn >> 6) == half) {
#pragma unroll
      for (int nt = 0; nt < 4; ++nt) {
        const int colL = nt * 16 + mi;                 // 0..63 within half
        const float bias = b1e[n0 + half * 64 + colL];
#pragma unroll
        for (int mt = 0; mt < 4; ++mt) {
#pragma unroll
          for (int r = 0; r < 4; ++r) {
            const int row = wm + mt * 16 + kq * 4 + r; // C/D: col=lane&15, row=quad*4+reg
            const float x = acc[mt][nt][r] + bias;
            const float g = 0.5f * x * (1.f + erff(x * 0.70710678118654752f));  // exact GELU
            cs[row * 66 + colL] = f2bf(wgt * g);
          }
        }
      }
    }
    __syncthreads();
#pragma unroll
    for (int i = 0; i < 4; ++i) {
      const int idx = i * 256 + tid;
      const int row = idx >> 3, c8 = (idx & 7) * 8;
      *(u16x8*)(C + (size_t)(m0 + row) * 3072 + n0 + half * 64 + c8) =
          *(const u16x8*)(cs + row * 66 + c8);
    }
  }
}

// ---------- GEMM2: split-K x4, 768 blocks, fp32 atomics ----------
// xcd=bid&7 (= batch), slot=bid>>3 (0..95), ks=slot/24, tt=slot%24,
// m0=(tt/6)*128, n0=(tt%6)*128. kslot=ks>>1 expert, kbase=(ks&1)*1536.
// B = w2t[e] [768][3072] bf16 (transposed). ks==0 adds weighted bias.
__global__ __launch_bounds__(256, 2) void gemm2_kernel(
    const u16* __restrict__ hbuf, const u16* __restrict__ w2t,
    const float* __restrict__ b2, float* __restrict__ out,
    const int* __restrict__ sel, const float* __restrict__ wsel) {
  __shared__ __align__(16) u16 smem[16384];  // 32 KB
  u16* As = smem;
  u16* Bs = smem + 8192;
  const int tid = threadIdx.x, bid = blockIdx.x;
  const int b = bid & 7, slot = bid >> 3;
  const int ks = slot / 24, tt = slot % 24;
  const int m0 = (tt / 6) * 128, n0 = (tt % 6) * 128;
  const int kslot = ks >> 1;
  const int e = sel[b * 2 + kslot];
  const u16* A = hbuf + (size_t)(b * 2 + kslot) * 512 * 3072;
  const u16* Bt = w2t + (size_t)e * 768 * 3072;   // [h=768][f=3072]
  const int kbase = (ks & 1) * 1536;
  const int lane = tid & 63, wv = tid >> 6;
  const int wm = (wv >> 1) * 64, wn = (wv & 1) * 64;
  const int mi = lane & 15, kq = lane >> 4;

  f32x4 acc[4][4] = {};
  GEMM_LOOP(24, A, 3072, m0, Bt, 3072, n0, kbase)

  float* C = out + (size_t)b * 512 * 768;
  const float w0 = wsel[b * 2 + 0], w1 = wsel[b * 2 + 1];
  const float* b2e0 = b2 + sel[b * 2 + 0] * 768;
  const float* b2e1 = b2 + sel[b * 2 + 1] * 768;
#pragma unroll
  for (int nt = 0; nt < 4; ++nt) {
    const int col = n0 + wn + nt * 16 + mi;
    const float bias = (ks == 0) ? (w0 * b2e0[col] + w1 * b2e1[col]) : 0.f;
#pragma unroll
    for (int mt = 0; mt < 4; ++mt) {
#pragma unroll
      for (int r = 0; r < 4; ++r) {
        const int row = m0 + wm + mt * 16 + kq * 4 + r;
        atomicAdd(&C[(size_t)row * 768 + col], acc[mt][nt][r] + bias);
      }
    }
  }
}

extern "C" void kernel_launch(void* const* d_in, const int* in_sizes, int n_in,
                              void* d_out, int out_size, void* d_ws, size_t ws_size,
                              hipStream_t stream) {
  const float* hidden = (const float*)d_in[0];  // [8,512,768] fp32
  const float* Wg     = (const float*)d_in[1];  // [768,8]
  const float* W1     = (const float*)d_in[2];  // [8,768,3072]
  const float* b1     = (const float*)d_in[3];  // [8,3072]
  const float* W2     = (const float*)d_in[4];  // [8,3072,768]
  const float* b2     = (const float*)d_in[5];  // [8,768]
  float* out = (float*)d_out;                   // [8,512,768] ++ logits [8,8]

  char* ws = (char*)d_ws;
  int*   sel    = (int*)ws;
  float* wsel   = (float*)(ws + 64);
  float* pooled = (float*)(ws + 128);
  u16* hbf  = (u16*)(ws + 32768);               // 6.29 MB bf16 hidden
  u16* w1t  = hbf + (size_t)8 * 512 * 768;      // 37.75 MB bf16 W1^T [3072][768]
  u16* w2t  = w1t + (size_t)8 * 768 * 3072;     // 37.75 MB bf16 W2^T [768][3072]
  u16* hbuf = w2t + (size_t)8 * 768 * 3072;     // 50.33 MB bf16 activations

  float* logits_out = out + (size_t)8 * 512 * 768;

  hipMemsetAsync(ws, 0, 32768, stream);                  // sel/wsel/pooled
  hipMemsetAsync(out, 0, (size_t)out_size * 4, stream);  // atomic accum base
  prep_kernel<<<2816, 256, 0, stream>>>(W1, w1t, hidden, hbf, pooled);
  router_final_kernel<<<1, 256, 0, stream>>>(pooled, Wg, logits_out, sel, wsel);
  gemm1_kernel<<<2304 + 1536, 256, 0, stream>>>(hbf, w1t, b1, hbuf, sel, wsel,
                                                W2, w2t, 2304);
  gemm2_kernel<<<768, 256, 0, stream>>>(hbuf, w2t, b2, out, sel, wsel);
}